// Round 3
// baseline (142.164 us; speedup 1.0000x reference)
//
#include <hip/hip_runtime.h>
#include <hip/hip_bf16.h>

#define BATCH 4096
#define DIM 64
#define KN 50
#define NL 3

typedef __attribute__((ext_vector_type(8))) short short8;   // 8 bf16 = 4 VGPRs
typedef __attribute__((ext_vector_type(4))) float f32x4;

// ---------------------------------------------------------------------------
// Kernel A: per-row fused gather + cumulative-mask neighbor sums + 3 MLP
// layers, emitting bf16 user/item embeddings for the MFMA scores GEMM.
// 1024 blocks x 256 threads; each of the 4 waves owns one batch row.
// W staged in LDS at stride 65 -> (lane+i)%32 banks, 2-way aliasing = free.
// xbuf is wave-private: no __syncthreads needed (lockstep wave, in-order LDS).
// ---------------------------------------------------------------------------
__global__ __launch_bounds__(256) void rows_kernel(
    const int* __restrict__ user_ids,
    const int* __restrict__ item_ids,
    const int* __restrict__ nbrs,
    const float* __restrict__ mask,
    const float* __restrict__ user_table,
    const float* __restrict__ item_table,
    const float* __restrict__ Ws,
    const float* __restrict__ bs,
    __hip_bfloat16* __restrict__ Uout,
    __hip_bfloat16* __restrict__ Iout)
{
    __shared__ float Wlds[NL * 64 * 65];   // 48.75 KB, padded
    __shared__ float blds[NL * 64];
    __shared__ float xbuf[4][64];

    const int tid = threadIdx.x;

    // Stage Ws [3][64][64] into padded LDS (coalesced global reads).
    for (int idx = tid; idx < NL * 64 * 64; idx += 256) {
        const int l = idx >> 12;
        const int rem = idx & 4095;
        const int j = rem >> 6;
        const int i = rem & 63;
        Wlds[l * (64 * 65) + j * 65 + i] = Ws[idx];
    }
    if (tid < NL * 64) blds[tid] = bs[tid];
    __syncthreads();

    const int wave = tid >> 6;
    const int lane = tid & 63;
    const int b = (blockIdx.x << 2) + wave;

    // Item embedding gather -> bf16.
    const int it = item_ids[b];
    Iout[b * DIM + lane] = __float2bfloat16(item_table[it * DIM + lane]);

    // User embedding.
    const int u = user_ids[b];
    float x = user_table[u * DIM + lane];

    // Lanes 0..49 hold this row's neighbor ids & weights.
    int ni = 0;
    float wi = 0.0f;
    if (lane < KN) {
        ni = nbrs[b * KN + lane];
        wi = mask[b * KN + lane];
    }

    // Layer l uses mask^(l+1): accumulate w, w^2, w^3 sums in one pass.
    float acc1 = 0.f, acc2 = 0.f, acc3 = 0.f;
    #pragma unroll
    for (int k = 0; k < KN; ++k) {
        const int nk = __shfl(ni, k);
        const float wk = __shfl(wi, k);
        const float v = user_table[nk * DIM + lane];
        const float w2 = wk * wk;
        acc1 = fmaf(wk, v, acc1);
        acc2 = fmaf(w2, v, acc2);
        acc3 = fmaf(w2 * wk, v, acc3);
    }
    const float inv = 1.0f / (float)KN;
    const float nm0 = acc1 * inv, nm1 = acc2 * inv, nm2 = acc3 * inv;

    // 3 layers: y_j = relu(b[j] + sum_i (x_i + n_i) * W[j][i])
    #pragma unroll
    for (int l = 0; l < NL; ++l) {
        const float nm = (l == 0) ? nm0 : (l == 1) ? nm1 : nm2;
        xbuf[wave][lane] = x + nm;        // wave-private; lgkmcnt ordering only
        float y = blds[l * 64 + lane];
        const float* wrow = &Wlds[l * (64 * 65) + lane * 65];
        #pragma unroll
        for (int i = 0; i < 64; ++i)
            y = fmaf(wrow[i], xbuf[wave][i], y);   // xbuf read = broadcast
        x = fmaxf(y, 0.0f);
    }
    Uout[b * DIM + lane] = __float2bfloat16(x);
}

// ---------------------------------------------------------------------------
// Kernel B: scores = U [4096,64] @ I^T via mfma_f32_16x16x32_bf16, zero LDS.
// OPERAND-SWAPPED: mfma(A=v_frag, B=u_frag) yields C^T fragments, so lane
// (quad,l16) holds C[row0+l16][col0+quad*4+reg], reg=0..3 -> one contiguous
// float4 store per tile (16 B/lane; wave covers 16 rows x 64 B/row segments).
// This replaces 4 strided dword stores per tile (store-issue bound before).
// A/B input frag (m89): m/n = lane&15, 8 contiguous k at (lane>>4)*8 -> one
// 16 B coalesced load per fragment; U,I are 512 KB each -> L2-resident.
// Grid 16x64 blocks; wave w owns rows [blockIdx.y*64+w*16, +16).
// ---------------------------------------------------------------------------
__global__ __launch_bounds__(256) void scores_kernel(
    const __hip_bfloat16* __restrict__ U,
    const __hip_bfloat16* __restrict__ V,
    float* __restrict__ C)
{
    const int tid = threadIdx.x;
    const int wave = tid >> 6;
    const int lane = tid & 63;
    const int quad = lane >> 4;
    const int l16 = lane & 15;

    const int row0 = (blockIdx.y << 6) + (wave << 4);
    const int colG = blockIdx.x << 8;

    const short* Us = (const short*)U;
    const short* Vs = (const short*)V;

    // U fragments for this wave's 16 rows (K=64 -> two k-halves), loop-invariant.
    const short* up = Us + (row0 + l16) * DIM + quad * 8;
    const short8 u0 = *(const short8*)(up);
    const short8 u1 = *(const short8*)(up + 32);

    #pragma unroll 4
    for (int ct = 0; ct < 16; ++ct) {
        const int col0 = colG + (ct << 4);
        const short* vp = Vs + (col0 + l16) * DIM + quad * 8;
        const short8 v0 = *(const short8*)(vp);
        const short8 v1 = *(const short8*)(vp + 32);
        f32x4 acc = {0.f, 0.f, 0.f, 0.f};
        // Swapped: A = V fragment, B = U fragment -> transposed C/D mapping.
        acc = __builtin_amdgcn_mfma_f32_16x16x32_bf16(v0, u0, acc, 0, 0, 0);
        acc = __builtin_amdgcn_mfma_f32_16x16x32_bf16(v1, u1, acc, 0, 0, 0);
        float* cp = C + (size_t)(row0 + l16) * BATCH + col0 + (quad << 2);
        *(float4*)cp = make_float4(acc[0], acc[1], acc[2], acc[3]);
    }
}

extern "C" void kernel_launch(void* const* d_in, const int* in_sizes, int n_in,
                              void* d_out, int out_size, void* d_ws, size_t ws_size,
                              hipStream_t stream)
{
    const int* user_ids   = (const int*)d_in[0];
    const int* item_ids   = (const int*)d_in[1];
    const int* nbrs       = (const int*)d_in[2];
    const float* mask     = (const float*)d_in[3];
    const float* utable   = (const float*)d_in[4];
    const float* itable   = (const float*)d_in[5];
    const float* Ws       = (const float*)d_in[6];
    const float* bs       = (const float*)d_in[7];
    float* out = (float*)d_out;

    __hip_bfloat16* Ubf = (__hip_bfloat16*)d_ws;        // [4096][64] bf16
    __hip_bfloat16* Ibf = Ubf + BATCH * DIM;            // [4096][64] bf16

    rows_kernel<<<BATCH / 4, 256, 0, stream>>>(user_ids, item_ids, nbrs, mask,
                                               utable, itable, Ws, bs, Ubf, Ibf);
    scores_kernel<<<dim3(16, 64), 256, 0, stream>>>(Ubf, Ibf, out);
}

// Round 4
// 139.794 us; speedup vs baseline: 1.0170x; 1.0170x over previous
//
#include <hip/hip_runtime.h>
#include <hip/hip_bf16.h>

#define BATCH 4096
#define DIM 64
#define KN 50
#define NL 3

typedef __attribute__((ext_vector_type(8))) short short8;   // 8 bf16 = 4 VGPRs
typedef __attribute__((ext_vector_type(4))) float f32x4;

// ---------------------------------------------------------------------------
// K1: gather. 1 row/wave, 1024 blocks x 256 thr (16 waves/CU), ZERO LDS ops.
// b is wave-uniform -> readfirstlane makes neighbor id/weight loads scalar
// (s_load, constant cache); the 50 row-gathers are independent vector loads.
// Layer l uses mask^(l+1) (cumulative re-masking) -> accumulate w,w^2,w^3
// sums in one pass. Emits X0 = u_emb + nm0 (fp32), NM1, NM2 (fp32), item bf16.
// ---------------------------------------------------------------------------
__global__ __launch_bounds__(256) void gather_kernel(
    const int* __restrict__ user_ids,
    const int* __restrict__ item_ids,
    const int* __restrict__ nbrs,
    const float* __restrict__ mask,
    const float* __restrict__ user_table,
    const float* __restrict__ item_table,
    float* __restrict__ X0,
    float* __restrict__ NM1,
    float* __restrict__ NM2,
    __hip_bfloat16* __restrict__ Iout)
{
    const int tid = threadIdx.x;
    const int wave = tid >> 6;
    const int lane = tid & 63;
    const int b = __builtin_amdgcn_readfirstlane((blockIdx.x << 2) + wave);

    // Item embedding gather -> bf16 (scalar id, coalesced row read).
    const int it = item_ids[b];
    Iout[b * DIM + lane] = __float2bfloat16(item_table[it * DIM + lane]);

    // User embedding.
    const int u = user_ids[b];
    const float x = user_table[u * DIM + lane];

    const int* __restrict__ nrow = nbrs + b * KN;    // uniform -> s_load
    const float* __restrict__ mrow = mask + b * KN;  // uniform -> s_load

    float acc1 = 0.f, acc2 = 0.f, acc3 = 0.f;
    #pragma unroll
    for (int k = 0; k < KN; ++k) {
        const int nk = nrow[k];          // SGPR
        const float wk = mrow[k];        // SGPR
        const float v = user_table[nk * DIM + lane];
        const float w2 = wk * wk;
        acc1 = fmaf(wk, v, acc1);
        acc2 = fmaf(w2, v, acc2);
        acc3 = fmaf(w2 * wk, v, acc3);
    }
    const float inv = 1.0f / (float)KN;
    X0[b * DIM + lane]  = x + acc1 * inv;   // layer-0 input, nm0 pre-added
    NM1[b * DIM + lane] = acc2 * inv;
    NM2[b * DIM + lane] = acc3 * inv;
}

// ---------------------------------------------------------------------------
// K2: 3-layer MLP, fp32. 4 rows/wave (W-read amortized 4x), 16 rows/block,
// grid 256. Per i: one ds_read_b32 of W (stride 65 -> bank (lane+i)%32,
// 2-way = free) + one 16B broadcast ds_read of the x-quad + 4 FMAs.
// x round-trips through a wave-private transposed quad buffer (no barriers).
// ---------------------------------------------------------------------------
__global__ __launch_bounds__(256) void mlp_kernel(
    const float* __restrict__ X0,
    const float* __restrict__ NM1,
    const float* __restrict__ NM2,
    const float* __restrict__ Ws,
    const float* __restrict__ bs,
    __hip_bfloat16* __restrict__ Uout)
{
    __shared__ float Wlds[NL * 64 * 65];     // 48.75 KB, padded
    __shared__ float blds[NL * 64];
    __shared__ float4 xb[4][64];             // [wave][i] = x quad (4 rows)

    const int tid = threadIdx.x;

    for (int idx = tid; idx < NL * 64 * 64; idx += 256) {
        const int l = idx >> 12;
        const int rem = idx & 4095;
        const int j = rem >> 6;
        const int i = rem & 63;
        Wlds[l * (64 * 65) + j * 65 + i] = Ws[idx];
    }
    if (tid < NL * 64) blds[tid] = bs[tid];
    __syncthreads();

    const int wave = tid >> 6;
    const int lane = tid & 63;
    const int r0 = (blockIdx.x << 4) + (wave << 2);   // 4 rows r0..r0+3

    float x0 = X0[(r0 + 0) * DIM + lane];
    float x1 = X0[(r0 + 1) * DIM + lane];
    float x2 = X0[(r0 + 2) * DIM + lane];
    float x3 = X0[(r0 + 3) * DIM + lane];

    #pragma unroll
    for (int l = 0; l < NL; ++l) {
        xb[wave][lane] = make_float4(x0, x1, x2, x3);  // wave-private
        float y0 = blds[l * 64 + lane], y1 = y0, y2 = y0, y3 = y0;
        const float* wrow = &Wlds[l * (64 * 65) + lane * 65];
        #pragma unroll
        for (int i = 0; i < 64; ++i) {
            const float w = wrow[i];             // conflict-free b32
            const float4 xv = xb[wave][i];       // 16B broadcast
            y0 = fmaf(w, xv.x, y0);
            y1 = fmaf(w, xv.y, y1);
            y2 = fmaf(w, xv.z, y2);
            y3 = fmaf(w, xv.w, y3);
        }
        if (l < NL - 1) {
            const float* NM = (l == 0) ? NM1 : NM2;
            x0 = fmaxf(y0, 0.f) + NM[(r0 + 0) * DIM + lane];
            x1 = fmaxf(y1, 0.f) + NM[(r0 + 1) * DIM + lane];
            x2 = fmaxf(y2, 0.f) + NM[(r0 + 2) * DIM + lane];
            x3 = fmaxf(y3, 0.f) + NM[(r0 + 3) * DIM + lane];
        } else {
            x0 = fmaxf(y0, 0.f); x1 = fmaxf(y1, 0.f);
            x2 = fmaxf(y2, 0.f); x3 = fmaxf(y3, 0.f);
        }
    }
    Uout[(r0 + 0) * DIM + lane] = __float2bfloat16(x0);
    Uout[(r0 + 1) * DIM + lane] = __float2bfloat16(x1);
    Uout[(r0 + 2) * DIM + lane] = __float2bfloat16(x2);
    Uout[(r0 + 3) * DIM + lane] = __float2bfloat16(x3);
}

// ---------------------------------------------------------------------------
// K3: scores = U [4096,64] @ I^T via mfma_f32_16x16x32_bf16, zero LDS.
// Operand-swapped (A=V,B=U) -> lane (quad,l16) holds C[row0+l16][col0+quad*4+r]
// -> one float4 store per tile. Write-bound (64 MiB C).
// ---------------------------------------------------------------------------
__global__ __launch_bounds__(256) void scores_kernel(
    const __hip_bfloat16* __restrict__ U,
    const __hip_bfloat16* __restrict__ V,
    float* __restrict__ C)
{
    const int tid = threadIdx.x;
    const int wave = tid >> 6;
    const int lane = tid & 63;
    const int quad = lane >> 4;
    const int l16 = lane & 15;

    const int row0 = (blockIdx.y << 6) + (wave << 4);
    const int colG = blockIdx.x << 8;

    const short* Us = (const short*)U;
    const short* Vs = (const short*)V;

    const short* up = Us + (row0 + l16) * DIM + quad * 8;
    const short8 u0 = *(const short8*)(up);
    const short8 u1 = *(const short8*)(up + 32);

    #pragma unroll 4
    for (int ct = 0; ct < 16; ++ct) {
        const int col0 = colG + (ct << 4);
        const short* vp = Vs + (col0 + l16) * DIM + quad * 8;
        const short8 v0 = *(const short8*)(vp);
        const short8 v1 = *(const short8*)(vp + 32);
        f32x4 acc = {0.f, 0.f, 0.f, 0.f};
        acc = __builtin_amdgcn_mfma_f32_16x16x32_bf16(v0, u0, acc, 0, 0, 0);
        acc = __builtin_amdgcn_mfma_f32_16x16x32_bf16(v1, u1, acc, 0, 0, 0);
        float* cp = C + (size_t)(row0 + l16) * BATCH + col0 + (quad << 2);
        *(float4*)cp = make_float4(acc[0], acc[1], acc[2], acc[3]);
    }
}

extern "C" void kernel_launch(void* const* d_in, const int* in_sizes, int n_in,
                              void* d_out, int out_size, void* d_ws, size_t ws_size,
                              hipStream_t stream)
{
    const int* user_ids   = (const int*)d_in[0];
    const int* item_ids   = (const int*)d_in[1];
    const int* nbrs       = (const int*)d_in[2];
    const float* mask     = (const float*)d_in[3];
    const float* utable   = (const float*)d_in[4];
    const float* itable   = (const float*)d_in[5];
    const float* Ws       = (const float*)d_in[6];
    const float* bs       = (const float*)d_in[7];
    float* out = (float*)d_out;

    float* X0  = (float*)d_ws;                           // [4096][64] f32
    float* NM1 = X0 + BATCH * DIM;                       // [4096][64] f32
    float* NM2 = NM1 + BATCH * DIM;                      // [4096][64] f32
    __hip_bfloat16* Ubf = (__hip_bfloat16*)(NM2 + BATCH * DIM);  // [4096][64] bf16
    __hip_bfloat16* Ibf = Ubf + BATCH * DIM;                     // [4096][64] bf16

    gather_kernel<<<BATCH / 4, 256, 0, stream>>>(user_ids, item_ids, nbrs, mask,
                                                 utable, itable, X0, NM1, NM2, Ibf);
    mlp_kernel<<<BATCH / 16, 256, 0, stream>>>(X0, NM1, NM2, Ws, bs, Ubf);
    scores_kernel<<<dim3(16, 64), 256, 0, stream>>>(Ubf, Ibf, out);
}